// Round 8
// baseline (914.094 us; speedup 1.0000x reference)
//
#include <hip/hip_runtime.h>
#include <math.h>

#define N_NODES 50000
#define N_EDGES 800000
#define IN_F 256
#define OUT_F 128
#define ALPHA 0.2f

#define GEMM_WAVES ((N_NODES + 31) / 32)              // 1563 (32 rows/wave)
#define GEMM_BLOCKS ((GEMM_WAVES + 3) / 4)            // 391

// spmm partition: 256 blocks x 196 destination nodes (1 block/CU, co-resident)
#define NPB 196
#define SPMM_BLOCKS 256                               // 256*196 = 50176 >= N
#define SPMM_THREADS 512
#define QCAP 4608                                     // per-block edges ~3140+-54; >6 sigma safe
#define NCOLU 400000                                  // N_EDGES/2 packed col pairs
#define PACK_BLOCKS ((NCOLU + 255) / 256)             // 1563

typedef short bf16x8 __attribute__((ext_vector_type(8)));
typedef float f32x4  __attribute__((ext_vector_type(4)));

// f32 -> bf16 round-to-nearest-even (no NaN handling needed here)
static __device__ __forceinline__ unsigned short f2bf(float f) {
    unsigned int u = __float_as_uint(f);
    u += 0x7FFFu + ((u >> 16) & 1u);
    return (unsigned short)(u >> 16);
}
static __device__ __forceinline__ float bf2f(unsigned int u16) {
    return __uint_as_float(u16 << 16);
}

// ---------------- K1: fused prep: col-pack + Wa + WbT ----------------
// blocks [0,1563): colpk[i] = u16(col[2i]) | u16(col[2i+1])<<16  (cols < 65536)
// block 1563: Wa = W @ a halves (f32 exact)
// blocks [1564,1692): WbT[n][k] = bf16(W[k][n]) (MFMA B-operand layout)
__global__ __launch_bounds__(256) void k_prep(const float* __restrict__ W,
                                              const float* __restrict__ a,
                                              const int* __restrict__ adj,
                                              float* __restrict__ Wa,
                                              unsigned short* __restrict__ WbT,
                                              unsigned int* __restrict__ colpk) {
    const int b = blockIdx.x, t = threadIdx.x;
    if (b < PACK_BLOCKS) {
        int i = b * 256 + t;
        if (i < NCOLU) {
            int2 c = ((const int2*)(adj + N_EDGES))[i];
            colpk[i] = (unsigned int)(c.x & 0xFFFF) | ((unsigned int)c.y << 16);
        }
    } else if (b == PACK_BLOCKS) {
        const int k = t;
        const float4* wr  = (const float4*)(W + (size_t)k * OUT_F);
        const float4* av1 = (const float4*)a;
        const float4* av2 = (const float4*)(a + OUT_F);
        float s1 = 0.0f, s2 = 0.0f;
#pragma unroll 8
        for (int i = 0; i < OUT_F / 4; ++i) {
            float4 w = wr[i], x = av1[i], y = av2[i];
            s1 = fmaf(w.x, x.x, fmaf(w.y, x.y, fmaf(w.z, x.z, fmaf(w.w, x.w, s1))));
            s2 = fmaf(w.x, y.x, fmaf(w.y, y.y, fmaf(w.z, y.z, fmaf(w.w, y.w, s2))));
        }
        Wa[k] = s1;
        Wa[IN_F + k] = s2;
    } else {
        const int n = b - (PACK_BLOCKS + 1);
        WbT[(size_t)n * IN_F + t] = f2bf(W[(size_t)t * OUT_F + n]);
    }
}

// ---------------- K2: Wh = h @ W via bf16 MFMA + fused f32 scores ----------
// One wave = 32 rows x 128 cols = 2 row-tiles x 8 col-tiles of 16x16x32 MFMA.
// No LDS. Scores use PRE-conversion f32 h against f32 Wa (exact).
__global__ __launch_bounds__(256) void k_gemm(const float* __restrict__ h,
                                              const unsigned short* __restrict__ WbT,
                                              const float* __restrict__ Wa,
                                              unsigned short* __restrict__ Whb,
                                              float* __restrict__ s_src,
                                              float* __restrict__ s_dst) {
    const int wid  = (blockIdx.x * blockDim.x + threadIdx.x) >> 6;
    const int lane = threadIdx.x & 63;
    if (wid >= GEMM_WAVES) return;
    const int m = lane & 15, grp = lane >> 4;
    const int row0 = wid * 32;

    f32x4 acc[2][8];
#pragma unroll
    for (int rt = 0; rt < 2; ++rt)
#pragma unroll
        for (int nt = 0; nt < 8; ++nt) acc[rt][nt] = (f32x4){0.f, 0.f, 0.f, 0.f};
    float sp1[2] = {0.f, 0.f}, sp2[2] = {0.f, 0.f};

    for (int kt = 0; kt < 8; ++kt) {
        const int k0 = kt * 32;
        bf16x8 hfrag[2];
#pragma unroll
        for (int rt = 0; rt < 2; ++rt) {
            int r = row0 + rt * 16 + m;
            if (r >= N_NODES) r = N_NODES - 1;   // clamp; stores guarded
            const float4* hp = (const float4*)(h + (size_t)r * IN_F + k0 + grp * 8);
            float4 x0 = hp[0], x1 = hp[1];
            const float4* wap1 = (const float4*)(Wa + k0 + grp * 8);
            const float4* wap2 = (const float4*)(Wa + IN_F + k0 + grp * 8);
            float4 a0 = wap1[0], a1 = wap1[1];
            float4 b0 = wap2[0], b1 = wap2[1];
            sp1[rt] = fmaf(x0.x, a0.x, fmaf(x0.y, a0.y, fmaf(x0.z, a0.z, fmaf(x0.w, a0.w, sp1[rt]))));
            sp1[rt] = fmaf(x1.x, a1.x, fmaf(x1.y, a1.y, fmaf(x1.z, a1.z, fmaf(x1.w, a1.w, sp1[rt]))));
            sp2[rt] = fmaf(x0.x, b0.x, fmaf(x0.y, b0.y, fmaf(x0.z, b0.z, fmaf(x0.w, b0.w, sp2[rt]))));
            sp2[rt] = fmaf(x1.x, b1.x, fmaf(x1.y, b1.y, fmaf(x1.z, b1.z, fmaf(x1.w, b1.w, sp2[rt]))));
            bf16x8 hf;
            hf[0] = (short)f2bf(x0.x); hf[1] = (short)f2bf(x0.y);
            hf[2] = (short)f2bf(x0.z); hf[3] = (short)f2bf(x0.w);
            hf[4] = (short)f2bf(x1.x); hf[5] = (short)f2bf(x1.y);
            hf[6] = (short)f2bf(x1.z); hf[7] = (short)f2bf(x1.w);
            hfrag[rt] = hf;
        }
#pragma unroll
        for (int nt = 0; nt < 8; ++nt) {
            bf16x8 wf = *(const bf16x8*)(WbT + (size_t)(nt * 16 + m) * IN_F + k0 + grp * 8);
            acc[0][nt] = __builtin_amdgcn_mfma_f32_16x16x32_bf16(wf, hfrag[0], acc[0][nt], 0, 0, 0);
            acc[1][nt] = __builtin_amdgcn_mfma_f32_16x16x32_bf16(wf, hfrag[1], acc[1][nt], 0, 0, 0);
        }
    }

#pragma unroll
    for (int rt = 0; rt < 2; ++rt) {
        const int row = row0 + rt * 16 + m;
        const bool valid = (row < N_NODES);
        float t1 = sp1[rt], t2 = sp2[rt];
        t1 += __shfl_xor(t1, 16); t1 += __shfl_xor(t1, 32);
        t2 += __shfl_xor(t2, 16); t2 += __shfl_xor(t2, 32);
        if (valid && grp == 0) { s_src[row] = t1; s_dst[row] = t2; }
        if (valid) {
            unsigned short* orow = Whb + (size_t)row * OUT_F;
#pragma unroll
            for (int nt = 0; nt < 8; ++nt) {
                f32x4 v = acc[rt][nt];
                ushort4 pk;
                pk.x = f2bf(v[0]); pk.y = f2bf(v[1]);
                pk.z = f2bf(v[2]); pk.w = f2bf(v[3]);
                *(ushort4*)(orow + nt * 16 + grp * 4) = pk;
            }
        }
    }
}

// ---------------- K3: destination-partitioned scan-SpMM ----------------
// Block owns 196 dest nodes + 100KB LDS f32 accumulator [196][128].
// Phase 1: self-loop init. Phase 2: scan packed u16 cols (L2 broadcast),
// push matching edge ids to LDS queue (4B entries, no global loads).
// Phase 3: resolve queue -> {src, ex}. Phase 4: per-wave batches of 8
// single-level Whb row loads, ds_add_f32 accumulate (2-way = free).
// Phase 5: normalize + ELU + coalesced store. No edge structure in HBM.
__global__ __launch_bounds__(SPMM_THREADS) void k_spmm(const int* __restrict__ adj,
                                                       const unsigned int* __restrict__ colpk,
                                                       const unsigned short* __restrict__ Whb,
                                                       const float* __restrict__ s_src,
                                                       const float* __restrict__ s_dst,
                                                       float* __restrict__ out) {
    __shared__ float accF[NPB][OUT_F];   // 100,352 B
    __shared__ uint2 q[QCAP];            // 36,864 B
    __shared__ float sdl[NPB];           // s_dst local
    __shared__ float dnm[NPB];           // softmax denominator
    __shared__ int qn;

    const int t = threadIdx.x;
    const int lo = blockIdx.x * NPB;
    const int wid = t >> 6, lane = t & 63;
    const uint* __restrict__ WhbU = (const uint*)Whb;  // ushort2 as uint, [N][64]

    // --- phase 1a: scores + self-loop exp ---
    if (t == 0) qn = 0;
    for (int ln = t; ln < NPB; ln += SPMM_THREADS) {
        int node = lo + ln;
        if (node < N_NODES) {
            float sd = s_dst[node];
            sdl[ln] = sd;
            float s0 = sd + s_src[node];
            float lr = (s0 > 0.0f) ? s0 : ALPHA * s0;
            dnm[ln] = __expf(lr);
        }
    }
    __syncthreads();
    // --- phase 1b: accumulator init with self-loop term ---
    for (int idx = t; idx < NPB * 64; idx += SPMM_THREADS) {
        int ln = idx >> 6, fp = idx & 63;
        int node = lo + ln;
        float vx = 0.0f, vy = 0.0f;
        if (node < N_NODES) {
            uint w = WhbU[(size_t)node * 64 + fp];
            float x0 = dnm[ln];
            vx = x0 * bf2f(w & 0xFFFFu);
            vy = x0 * bf2f(w >> 16);
        }
        accF[ln][fp * 2]     = vx;
        accF[ln][fp * 2 + 1] = vy;
    }

    // --- phase 2: scan packed cols, push edge ids (e<2^20, cl<256) ---
    for (int i = t; i < NCOLU; i += SPMM_THREADS) {
        unsigned int cpk = colpk[i];
        unsigned int d0 = (cpk & 0xFFFFu) - (unsigned int)lo;
        unsigned int d1 = (cpk >> 16) - (unsigned int)lo;
        if (d0 < (unsigned int)NPB) {
            int p = atomicAdd(&qn, 1);
            if (p < QCAP) q[p].x = (unsigned int)(2 * i) | (d0 << 20);
        }
        if (d1 < (unsigned int)NPB) {
            int p = atomicAdd(&qn, 1);
            if (p < QCAP) q[p].x = (unsigned int)(2 * i + 1) | (d1 << 20);
        }
    }
    __syncthreads();
    int Q = min(qn, QCAP - 64);
    int Qr = (Q + 63) & ~63;
    // pad with zero-weight dummies (src=0, cl=0, ex=0) -> branch-free phase 4
    for (int k = Q + t; k < Qr; k += SPMM_THREADS) q[k] = make_uint2(0u, 0u);

    // --- phase 3: resolve queue entries -> {src|cl<<16, ex} ---
    for (int k = t; k < Q; k += SPMM_THREADS) {
        unsigned int ent = q[k].x;
        int e  = ent & 0xFFFFFu;
        int cl = ent >> 20;
        int src = adj[e];
        float s = sdl[cl] + s_src[src];
        float lr = (s > 0.0f) ? s : ALPHA * s;
        float ex = __expf(lr);
        q[k] = make_uint2((unsigned int)src | ((unsigned int)cl << 16),
                          __float_as_uint(ex));
    }
    __syncthreads();

    // --- phase 4: batched row-gather + LDS accumulate (8 rows in flight) ---
    for (int base = wid * 8; base < Qr; base += 64) {
        uint2 qe[8];
#pragma unroll
        for (int k = 0; k < 8; ++k) qe[k] = q[base + k];   // LDS broadcast
        uint wv[8];
#pragma unroll
        for (int k = 0; k < 8; ++k)
            wv[k] = WhbU[(size_t)(qe[k].x & 0xFFFFu) * 64 + lane];
        if (lane < 8) {
            uint2 e = q[base + lane];
            atomicAdd(&dnm[e.x >> 16], __uint_as_float(e.y));
        }
#pragma unroll
        for (int k = 0; k < 8; ++k) {
            float ex = __uint_as_float(qe[k].y);
            int cl = qe[k].x >> 16;
            atomicAdd(&accF[cl][lane * 2],     ex * bf2f(wv[k] & 0xFFFFu));
            atomicAdd(&accF[cl][lane * 2 + 1], ex * bf2f(wv[k] >> 16));
        }
    }
    __syncthreads();

    // --- phase 5: normalize, ELU, coalesced store ---
    for (int idx = t; idx < NPB * 64; idx += SPMM_THREADS) {
        int ln = idx >> 6, fp = idx & 63;
        int node = lo + ln;
        if (node >= N_NODES) continue;
        float inv = 1.0f / dnm[ln];
        float vx = accF[ln][fp * 2] * inv;
        float vy = accF[ln][fp * 2 + 1] * inv;
        vx = (vx > 0.0f) ? vx : expm1f(vx);
        vy = (vy > 0.0f) ? vy : expm1f(vy);
        ((float2*)(out + (size_t)node * OUT_F))[fp] = make_float2(vx, vy);
    }
}

// ---------------- launcher ----------------
extern "C" void kernel_launch(void* const* d_in, const int* in_sizes, int n_in,
                              void* d_out, int out_size, void* d_ws, size_t ws_size,
                              hipStream_t stream) {
    const float* h   = (const float*)d_in[0];
    const int*   adj = (const int*)d_in[1];
    const float* W   = (const float*)d_in[2];
    const float* a   = (const float*)d_in[3];
    float* out = (float*)d_out;

    // workspace layout (256B-aligned chunks)
    char* ws = (char*)d_ws;
    const size_t SZ_WHB = (size_t)N_NODES * OUT_F * 2;   // 12,800,000 (mult of 256)
    const size_t SZ_N   = 200704;                        // >= N_NODES*4, 256-aligned
    unsigned short* Whb = (unsigned short*)(ws);
    float* s_src   = (float*)(ws + SZ_WHB);
    float* s_dst   = (float*)(ws + SZ_WHB + SZ_N);
    float* Wa      = (float*)(ws + SZ_WHB + 2 * SZ_N);                       // 2KB
    unsigned short* WbT  = (unsigned short*)(ws + SZ_WHB + 2 * SZ_N + 2048); // 64KB
    unsigned int*   colpk = (unsigned int*)(ws + SZ_WHB + 2 * SZ_N + 2048 + 65536);

    (void)in_sizes; (void)n_in; (void)out_size; (void)ws_size;

    k_prep<<<PACK_BLOCKS + 1 + OUT_F, 256, 0, stream>>>(W, a, adj, Wa, WbT, colpk);
    k_gemm<<<GEMM_BLOCKS, 256, 0, stream>>>(h, WbT, Wa, Whb, s_src, s_dst);
    k_spmm<<<SPMM_BLOCKS, SPMM_THREADS, 0, stream>>>(adj, colpk, Whb, s_src, s_dst, out);
}

// Round 10
// 203.744 us; speedup vs baseline: 4.4865x; 4.4865x over previous
//
#include <hip/hip_runtime.h>
#include <math.h>

#define N_NODES 50000
#define N_EDGES 800000
#define IN_F 256
#define OUT_F 128
#define ALPHA 0.2f

#define GEMM_WAVES ((N_NODES + 31) / 32)              // 1563 (32 rows/wave)
#define GEMM_BLOCKS ((GEMM_WAVES + 3) / 4)            // 391
#define NODE_BLOCKS ((N_NODES + 255) / 256)           // 196

typedef short bf16x8 __attribute__((ext_vector_type(8)));
typedef float f32x4  __attribute__((ext_vector_type(4)));

// f32 -> bf16 round-to-nearest-even (no NaN handling needed here)
static __device__ __forceinline__ unsigned short f2bf(float f) {
    unsigned int u = __float_as_uint(f);
    u += 0x7FFFu + ((u >> 16) & 1u);
    return (unsigned short)(u >> 16);
}
static __device__ __forceinline__ float bf2f(unsigned int u16) {
    return __uint_as_float(u16 << 16);
}

// ---------------- K1: fused init + Wa + WbT prep ----------------
// blocks [0,196): head init; block 196: Wa = W@a halves;
// blocks [197,325): WbT[n][k] = bf16(W[k][n]) (MFMA B-operand layout).
__global__ __launch_bounds__(256) void k_prep(const float* __restrict__ W,
                                              const float* __restrict__ a,
                                              int* __restrict__ head,
                                              float* __restrict__ Wa,
                                              unsigned short* __restrict__ WbT) {
    const int b = blockIdx.x, t = threadIdx.x;
    if (b < NODE_BLOCKS) {
        int i = b * 256 + t;
        if (i < N_NODES) head[i] = -1;
    } else if (b == NODE_BLOCKS) {
        const int k = t;
        const float4* wr  = (const float4*)(W + (size_t)k * OUT_F);
        const float4* av1 = (const float4*)a;
        const float4* av2 = (const float4*)(a + OUT_F);
        float s1 = 0.0f, s2 = 0.0f;
#pragma unroll 8
        for (int i = 0; i < OUT_F / 4; ++i) {
            float4 w = wr[i], x = av1[i], y = av2[i];
            s1 = fmaf(w.x, x.x, fmaf(w.y, x.y, fmaf(w.z, x.z, fmaf(w.w, x.w, s1))));
            s2 = fmaf(w.x, y.x, fmaf(w.y, y.y, fmaf(w.z, y.z, fmaf(w.w, y.w, s2))));
        }
        Wa[k] = s1;
        Wa[IN_F + k] = s2;
    } else {
        const int n = b - (NODE_BLOCKS + 1);
        WbT[(size_t)n * IN_F + t] = f2bf(W[(size_t)t * OUT_F + n]);
    }
}

// ---------------- K2: Wh = h @ W via bf16 MFMA + fused f32 scores ----------
// One wave = 32 rows x 128 cols = 2 row-tiles x 8 col-tiles of 16x16x32 MFMA.
// No LDS. Scores use PRE-conversion f32 h against f32 Wa (exact).
__global__ __launch_bounds__(256) void k_gemm(const float* __restrict__ h,
                                              const unsigned short* __restrict__ WbT,
                                              const float* __restrict__ Wa,
                                              unsigned short* __restrict__ Whb,
                                              float* __restrict__ s_src,
                                              float* __restrict__ s_dst) {
    const int wid  = (blockIdx.x * blockDim.x + threadIdx.x) >> 6;
    const int lane = threadIdx.x & 63;
    if (wid >= GEMM_WAVES) return;
    const int m = lane & 15, grp = lane >> 4;
    const int row0 = wid * 32;

    f32x4 acc[2][8];
#pragma unroll
    for (int rt = 0; rt < 2; ++rt)
#pragma unroll
        for (int nt = 0; nt < 8; ++nt) acc[rt][nt] = (f32x4){0.f, 0.f, 0.f, 0.f};
    float sp1[2] = {0.f, 0.f}, sp2[2] = {0.f, 0.f};

    for (int kt = 0; kt < 8; ++kt) {
        const int k0 = kt * 32;
        bf16x8 hfrag[2];
#pragma unroll
        for (int rt = 0; rt < 2; ++rt) {
            int r = row0 + rt * 16 + m;
            if (r >= N_NODES) r = N_NODES - 1;   // clamp; stores guarded
            const float4* hp = (const float4*)(h + (size_t)r * IN_F + k0 + grp * 8);
            float4 x0 = hp[0], x1 = hp[1];
            const float4* wap1 = (const float4*)(Wa + k0 + grp * 8);
            const float4* wap2 = (const float4*)(Wa + IN_F + k0 + grp * 8);
            float4 a0 = wap1[0], a1 = wap1[1];
            float4 b0 = wap2[0], b1 = wap2[1];
            sp1[rt] = fmaf(x0.x, a0.x, fmaf(x0.y, a0.y, fmaf(x0.z, a0.z, fmaf(x0.w, a0.w, sp1[rt]))));
            sp1[rt] = fmaf(x1.x, a1.x, fmaf(x1.y, a1.y, fmaf(x1.z, a1.z, fmaf(x1.w, a1.w, sp1[rt]))));
            sp2[rt] = fmaf(x0.x, b0.x, fmaf(x0.y, b0.y, fmaf(x0.z, b0.z, fmaf(x0.w, b0.w, sp2[rt]))));
            sp2[rt] = fmaf(x1.x, b1.x, fmaf(x1.y, b1.y, fmaf(x1.z, b1.z, fmaf(x1.w, b1.w, sp2[rt]))));
            bf16x8 hf;
            hf[0] = (short)f2bf(x0.x); hf[1] = (short)f2bf(x0.y);
            hf[2] = (short)f2bf(x0.z); hf[3] = (short)f2bf(x0.w);
            hf[4] = (short)f2bf(x1.x); hf[5] = (short)f2bf(x1.y);
            hf[6] = (short)f2bf(x1.z); hf[7] = (short)f2bf(x1.w);
            hfrag[rt] = hf;
        }
#pragma unroll
        for (int nt = 0; nt < 8; ++nt) {
            bf16x8 wf = *(const bf16x8*)(WbT + (size_t)(nt * 16 + m) * IN_F + k0 + grp * 8);
            acc[0][nt] = __builtin_amdgcn_mfma_f32_16x16x32_bf16(wf, hfrag[0], acc[0][nt], 0, 0, 0);
            acc[1][nt] = __builtin_amdgcn_mfma_f32_16x16x32_bf16(wf, hfrag[1], acc[1][nt], 0, 0, 0);
        }
    }

#pragma unroll
    for (int rt = 0; rt < 2; ++rt) {
        const int row = row0 + rt * 16 + m;
        const bool valid = (row < N_NODES);
        float t1 = sp1[rt], t2 = sp2[rt];
        t1 += __shfl_xor(t1, 16); t1 += __shfl_xor(t1, 32);
        t2 += __shfl_xor(t2, 16); t2 += __shfl_xor(t2, 32);
        if (valid && grp == 0) { s_src[row] = t1; s_dst[row] = t2; }
        if (valid) {
            unsigned short* orow = Whb + (size_t)row * OUT_F;
#pragma unroll
            for (int nt = 0; nt < 8; ++nt) {
                f32x4 v = acc[rt][nt];
                ushort4 pk;
                pk.x = f2bf(v[0]); pk.y = f2bf(v[1]);
                pk.z = f2bf(v[2]); pk.w = f2bf(v[3]);
                *(ushort4*)(orow + nt * 16 + grp * 4) = pk;
            }
        }
    }
}

// ---------------- K3: build per-destination linked lists (1 atomic/edge) ---
__global__ __launch_bounds__(256) void k_link(const int* __restrict__ adj,
                                              int* __restrict__ head,
                                              int2* __restrict__ list) {
    int e = blockIdx.x * blockDim.x + threadIdx.x;
    if (e >= N_EDGES) return;
    int src = adj[e];
    int col = adj[N_EDGES + e];
    int old = atomicExch(&head[col], e);   // only scattered atomic in pipeline
    list[e] = make_int2(src, old);         // coalesced by edge id
}

// ---------------- K4: chase-gather, 4 nodes/wave, softmax, ELU ----------
// 4 independent pointer chases per wave (vs 2 in R4): quad grp owns one
// node, 16 lanes x uint4 = 256B bf16 row. Chase latency halved per node.
// Softmax denom accumulated in-loop; self-loop folded analytically.
__global__ __launch_bounds__(256) void k_gather(const unsigned short* __restrict__ Whb,
                                                const int* __restrict__ head,
                                                const int2* __restrict__ list,
                                                const float* __restrict__ s_src,
                                                const float* __restrict__ s_dst,
                                                float* __restrict__ out) {
    int wid  = (blockIdx.x * blockDim.x + threadIdx.x) >> 6;
    int lane = threadIdx.x & 63;
    int grp  = lane >> 4;        // 0..3: node within quad
    int l    = lane & 15;        // 16 lanes x 16B = 256B row
    int node = wid * 4 + grp;
    if (node >= N_NODES) return;

    float sd = s_dst[node];
    // self-loop contribution
    float s0 = sd + s_src[node];
    float lr0 = (s0 > 0.0f) ? s0 : ALPHA * s0;
    float x0 = __expf(lr0);
    uint4 w0 = ((const uint4*)(Whb + (size_t)node * OUT_F))[l];
    float a0 = x0 * bf2f(w0.x & 0xFFFFu);
    float a1 = x0 * bf2f(w0.x >> 16);
    float a2 = x0 * bf2f(w0.y & 0xFFFFu);
    float a3 = x0 * bf2f(w0.y >> 16);
    float a4 = x0 * bf2f(w0.z & 0xFFFFu);
    float a5 = x0 * bf2f(w0.z >> 16);
    float a6 = x0 * bf2f(w0.w & 0xFFFFu);
    float a7 = x0 * bf2f(w0.w >> 16);
    float dsum = x0;

    int e = head[node];
    while (e >= 0) {
        int2 rec = list[e];      // {src, next}
        e = rec.y;               // advance chase ASAP
        float ss = s_src[rec.x];
        uint4 wv = ((const uint4*)(Whb + (size_t)rec.x * OUT_F))[l];
        float s = sd + ss;
        float lr = (s > 0.0f) ? s : ALPHA * s;
        float x = __expf(lr);
        a0 = fmaf(x, bf2f(wv.x & 0xFFFFu), a0);
        a1 = fmaf(x, bf2f(wv.x >> 16), a1);
        a2 = fmaf(x, bf2f(wv.y & 0xFFFFu), a2);
        a3 = fmaf(x, bf2f(wv.y >> 16), a3);
        a4 = fmaf(x, bf2f(wv.z & 0xFFFFu), a4);
        a5 = fmaf(x, bf2f(wv.z >> 16), a5);
        a6 = fmaf(x, bf2f(wv.w & 0xFFFFu), a6);
        a7 = fmaf(x, bf2f(wv.w >> 16), a7);
        dsum += x;
    }

    float inv = 1.0f / dsum;
    float4 o0, o1;
    o0.x = a0 * inv; o0.y = a1 * inv; o0.z = a2 * inv; o0.w = a3 * inv;
    o1.x = a4 * inv; o1.y = a5 * inv; o1.z = a6 * inv; o1.w = a7 * inv;
    o0.x = (o0.x > 0.0f) ? o0.x : expm1f(o0.x);
    o0.y = (o0.y > 0.0f) ? o0.y : expm1f(o0.y);
    o0.z = (o0.z > 0.0f) ? o0.z : expm1f(o0.z);
    o0.w = (o0.w > 0.0f) ? o0.w : expm1f(o0.w);
    o1.x = (o1.x > 0.0f) ? o1.x : expm1f(o1.x);
    o1.y = (o1.y > 0.0f) ? o1.y : expm1f(o1.y);
    o1.z = (o1.z > 0.0f) ? o1.z : expm1f(o1.z);
    o1.w = (o1.w > 0.0f) ? o1.w : expm1f(o1.w);
    float4* op = (float4*)(out + (size_t)node * OUT_F + l * 8);
    op[0] = o0;
    op[1] = o1;
}

// ---------------- launcher ----------------
extern "C" void kernel_launch(void* const* d_in, const int* in_sizes, int n_in,
                              void* d_out, int out_size, void* d_ws, size_t ws_size,
                              hipStream_t stream) {
    const float* h   = (const float*)d_in[0];
    const int*   adj = (const int*)d_in[1];
    const float* W   = (const float*)d_in[2];
    const float* a   = (const float*)d_in[3];
    float* out = (float*)d_out;

    // workspace layout (256B-aligned chunks)
    char* ws = (char*)d_ws;
    const size_t SZ_WHB = (size_t)N_NODES * OUT_F * 2;   // 12,800,000 (mult of 256)
    const size_t SZ_N   = 200704;                        // >= N_NODES*4, 256-aligned
    unsigned short* Whb = (unsigned short*)(ws);
    float* s_src   = (float*)(ws + SZ_WHB);
    float* s_dst   = (float*)(ws + SZ_WHB + SZ_N);
    int*   head    = (int*)  (ws + SZ_WHB + 2 * SZ_N);
    float* Wa      = (float*)(ws + SZ_WHB + 3 * SZ_N);                       // 2KB
    unsigned short* WbT = (unsigned short*)(ws + SZ_WHB + 3 * SZ_N + 2048);  // 64KB
    int2*  list    = (int2*) (ws + SZ_WHB + 3 * SZ_N + 2048 + 65536);        // 6.4MB

    (void)in_sizes; (void)n_in; (void)out_size; (void)ws_size;

    k_prep  <<<NODE_BLOCKS + 1 + OUT_F, 256, 0, stream>>>(W, a, head, Wa, WbT);
    k_gemm  <<<GEMM_BLOCKS, 256, 0, stream>>>(h, WbT, Wa, Whb, s_src, s_dst);
    k_link  <<<(N_EDGES + 255) / 256, 256, 0, stream>>>(adj, head, list);
    k_gather<<<((N_NODES + 3) / 4 * 64 + 255) / 256, 256, 0, stream>>>(Whb, head, list,
                                                                       s_src, s_dst, out);
}